// Round 6
// baseline (129.002 us; speedup 1.0000x reference)
//
#include <hip/hip_runtime.h>
#include <stdint.h>

// KANLinear: y = silu(x) @ W_b^T + einsum('big,oig->bo', bases(x), W_s * scaler)
// R5: FUSED — A-tiles (silu | spline bases) computed in-kernel from x into LDS
// (no 151MB Act materialization). B = Wc (pre-XOR-swizzled bf16) staged via
// global_load_lds, double-buffered. BM64xBN256, 4 waves, 2 blocks/CU.

#define IN_F   512
#define OUT_F  512
#define KDIM   4608
#define BATCH  16384

#define BM 64
#define BN 256
#define BK 64
#define NT (KDIM / BK)                 // 72
#define NSILU 8                        // tiles with k < 512
#define A_ELEMS (BM * BK)              // 4096 elems = 8 KiB
#define B_ELEMS (BN * BK)              // 16384 elems = 32 KiB

typedef unsigned short u16;
typedef short s16x8 __attribute__((ext_vector_type(8)));
typedef float f32x4 __attribute__((ext_vector_type(4)));

__device__ __forceinline__ u16 f2bf(float f) {
    uint32_t u = __builtin_bit_cast(uint32_t, f);
    uint32_t r = (u + 0x7FFFu + ((u >> 16) & 1u)) >> 16;   // RNE
    return (u16)r;
}

__device__ __forceinline__ float cleanx(float v) {
    if (v != v) v = 0.0f;                          // nan -> 0
    v = fminf(fmaxf(v, -6.0f), 6.0f);              // folds +-inf
    return fminf(fmaxf(v, -1.1f), 1.1f);           // grid clamp
}

// 8 cubic B-spline bases of one x value, packed as 8 bf16 (uint4).
// Uniform knots t_j = -2.2 + 0.4*j; after clip x in [t_2, t_9).
__device__ __forceinline__ uint4 bases8(float v) {
    v = cleanx(v);
    float t = (v + 2.2f) * 2.5f;
    int mm = (int)floorf(t);
    mm = min(max(mm, 2), 8);
    float u = t - (float)mm;
    float u2 = u * u;
    float u3 = u2 * u;
    float p0 = u3 * (1.0f / 6.0f);                              // g = mm
    float p1 = (1.0f + 3.0f * u + 3.0f * u2 - 3.0f * u3) * (1.0f / 6.0f); // g = mm-1
    float p2 = (4.0f - 6.0f * u2 + 3.0f * u3) * (1.0f / 6.0f);  // g = mm-2
    float w1 = 1.0f - u;
    float p3 = w1 * w1 * w1 * (1.0f / 6.0f);                    // g = mm-3
    union { u16 us[8]; uint4 q; } pk;
    #pragma unroll
    for (int g = 0; g < 8; ++g) {
        float r = 0.0f;
        r = (mm == g    ) ? p0 : r;
        r = (mm == g + 1) ? p1 : r;
        r = (mm == g + 2) ? p2 : r;
        r = (mm == g + 3) ? p3 : r;
        pk.us[g] = f2bf(r);
    }
    return pk.q;
}

// ---------------- weight prep: Wc[o][k] bf16 (pre-XOR-swizzled rows) -----------
__global__ void prep_w_kernel(const float* __restrict__ bw,
                              const float* __restrict__ sw,
                              const float* __restrict__ sc,
                              u16* __restrict__ Wc) {
    int idx = blockIdx.x * 256 + threadIdx.x;      // (o,i), 512*512 threads
    int o = idx >> 9;
    int i = idx & 511;
    int swz = o & 7;
    Wc[(size_t)o * KDIM + (i ^ (swz << 3))] = f2bf(bw[idx]);
    float s = sc[idx];
    const float4* sp = reinterpret_cast<const float4*>(sw + (size_t)idx * 8);
    float4 a = sp[0];
    float4 b = sp[1];
    union { u16 us[8]; uint4 v; } pk;
    pk.us[0] = f2bf(a.x * s); pk.us[1] = f2bf(a.y * s);
    pk.us[2] = f2bf(a.z * s); pk.us[3] = f2bf(a.w * s);
    pk.us[4] = f2bf(b.x * s); pk.us[5] = f2bf(b.y * s);
    pk.us[6] = f2bf(b.z * s); pk.us[7] = f2bf(b.w * s);
    *reinterpret_cast<uint4*>(Wc + (size_t)o * KDIM + IN_F + (size_t)(i ^ swz) * 8) = pk.v;
}

// ---------------- fused GEMM: C = [silu(x)|bases(x)] @ Wc^T --------------------
__global__ __launch_bounds__(256, 2) void kan_fused_kernel(const float* __restrict__ x,
                                                           const u16* __restrict__ Bw,
                                                           float* __restrict__ C) {
    __shared__ u16 As[A_ELEMS];            // 8 KiB, single-buffered (rebuilt per tile)
    __shared__ u16 Bs[2 * B_ELEMS];        // 64 KiB, double-buffered

    const int tid  = threadIdx.x;
    const int w    = tid >> 6;             // wave 0..3 -> N-split
    const int lane = tid & 63;

    // XCD-bijective swizzle, nwg = 512 (%8 == 0); N-sibling pairs adjacent
    const int bid = blockIdx.x;
    const int wg  = (bid & 7) * 64 + (bid >> 3);
    const int bm0 = (wg >> 1) * BM;
    const int bn0 = (wg & 1) * BN;

    const int wc   = w * 64;               // wave's 64 output cols
    const int rA   = lane & 15;
    const int sK   = (rA & 7) << 3;        // read-side XOR swizzle (elements)
    const int kgrp = (lane >> 4) * 8;

    // A-production mapping: this thread produces LDS row rL (= lane), col-seg w
    const int rL   = lane;                 // 0..63
    const int swzR = (rL & 7) << 3;        // write-side XOR swizzle
    const float* xrow = x + (size_t)(bm0 + rL) * IN_F;

    f32x4 acc[4][4] = {};

    auto stageB = [&](u16* dst, int kt) {
        #pragma unroll
        for (int c = 0; c < 8; ++c) {
            int off = tid * 8 + c * 2048;
            int row = off >> 6, col = off & 63;
            const u16* g = Bw + (size_t)(bn0 + row) * KDIM + kt * BK + col;
            __builtin_amdgcn_global_load_lds(
                (const __attribute__((address_space(1))) uint32_t*)g,
                (__attribute__((address_space(3))) uint32_t*)(dst + off), 16, 0, 0);
        }
    };

    // prologue: B(0) staged; x for tile 0 (silu: cols w*16 .. +16)
    stageB(Bs, 0);
    float4 q0, q1, q2, q3;                 // silu prefetch (16 floats)
    float  sa = 0.f, sb = 0.f;             // spline prefetch (2 scalars)
    {
        const float4* xp = reinterpret_cast<const float4*>(xrow + w * 16);
        q0 = xp[0]; q1 = xp[1]; q2 = xp[2]; q3 = xp[3];
    }

    for (int t = 0; t < NT; ++t) {
        __builtin_amdgcn_s_barrier();      // prev tile's LDS reads complete

        // ---- produce A(t) into LDS from prefetched x ----
        if (t < NSILU) {
            float vv[16] = {q0.x,q0.y,q0.z,q0.w, q1.x,q1.y,q1.z,q1.w,
                            q2.x,q2.y,q2.z,q2.w, q3.x,q3.y,q3.z,q3.w};
            union { u16 us[16]; uint4 q[2]; } pk;
            #pragma unroll
            for (int e = 0; e < 16; ++e) {
                float v = cleanx(vv[e]);
                pk.us[e] = f2bf(v / (1.0f + __expf(-v)));
            }
            *reinterpret_cast<uint4*>(&As[rL * BK + ((w * 16)     ^ swzR)]) = pk.q[0];
            *reinterpret_cast<uint4*>(&As[rL * BK + ((w * 16 + 8) ^ swzR)]) = pk.q[1];
        } else {
            uint4 b0 = bases8(sa);
            uint4 b1 = bases8(sb);
            *reinterpret_cast<uint4*>(&As[rL * BK + (( w      * 8) ^ swzR)]) = b0;
            *reinterpret_cast<uint4*>(&As[rL * BK + (((w + 4) * 8) ^ swzR)]) = b1;
        }

        // ---- stage B(t+1), then waits ----
        if (t + 1 < NT) {
            stageB(Bs + ((t + 1) & 1) * B_ELEMS, t + 1);
            asm volatile("s_waitcnt lgkmcnt(0)" ::: "memory");   // A writes visible
            asm volatile("s_waitcnt vmcnt(8)"   ::: "memory");   // B(t) landed, B(t+1) in flight
        } else {
            asm volatile("s_waitcnt lgkmcnt(0)" ::: "memory");
            asm volatile("s_waitcnt vmcnt(0)"   ::: "memory");
        }
        __builtin_amdgcn_s_barrier();      // A(t), B(t) visible to all waves

        // ---- fragments ----
        const u16* Bs_ = Bs + (t & 1) * B_ELEMS;
        s16x8 af[4][2], bf[2][4];
        #pragma unroll
        for (int kk = 0; kk < 2; ++kk) {
            const int kc = (kk * 32 + kgrp) ^ sK;
            #pragma unroll
            for (int m = 0; m < 4; ++m)
                af[m][kk] = *reinterpret_cast<const s16x8*>(&As[(m * 16 + rA) * BK + kc]);
            #pragma unroll
            for (int n = 0; n < 4; ++n)
                bf[kk][n] = *reinterpret_cast<const s16x8*>(&Bs_[(wc + n * 16 + rA) * BK + kc]);
        }

        // ---- prefetch x for tile t+1 (hidden under MFMA) ----
        if (t + 1 < NSILU) {
            const float4* xp = reinterpret_cast<const float4*>(xrow + (t + 1) * BK + w * 16);
            q0 = xp[0]; q1 = xp[1]; q2 = xp[2]; q3 = xp[3];
        } else if (t + 1 < NT) {
            const int ib = (t + 1) * 8 - 64;           // i base for tile t+1
            sa = xrow[ib + w];
            sb = xrow[ib + w + 4];
        }

        // ---- MFMA cluster ----
        __builtin_amdgcn_s_setprio(1);
        #pragma unroll
        for (int kk = 0; kk < 2; ++kk)
            #pragma unroll
            for (int m = 0; m < 4; ++m)
                #pragma unroll
                for (int n = 0; n < 4; ++n)
                    acc[m][n] = __builtin_amdgcn_mfma_f32_16x16x32_bf16(
                        af[m][kk], bf[kk][n], acc[m][n], 0, 0, 0);
        __builtin_amdgcn_s_setprio(0);
    }

    // epilogue: C/D layout col = lane&15, row = (lane>>4)*4 + reg
    const int rq = lane >> 4;
    const int cn = lane & 15;
    #pragma unroll
    for (int am = 0; am < 4; ++am) {
        #pragma unroll
        for (int an = 0; an < 4; ++an) {
            const int row0 = bm0 + am * 16 + rq * 4;
            const int col  = bn0 + wc + an * 16 + cn;
            float* cp = C + (size_t)row0 * OUT_F + col;
            cp[0 * OUT_F] = acc[am][an][0];
            cp[1 * OUT_F] = acc[am][an][1];
            cp[2 * OUT_F] = acc[am][an][2];
            cp[3 * OUT_F] = acc[am][an][3];
        }
    }
}

extern "C" void kernel_launch(void* const* d_in, const int* in_sizes, int n_in,
                              void* d_out, int out_size, void* d_ws, size_t ws_size,
                              hipStream_t stream) {
    const float* x  = (const float*)d_in[0];
    const float* bw = (const float*)d_in[1];
    const float* sw = (const float*)d_in[2];
    const float* sc = (const float*)d_in[3];
    // d_in[4] (grid) unused: uniform knots by construction

    u16* Wc = (u16*)d_ws;                          // 512*4608*2 = 4.7 MB

    prep_w_kernel<<<(OUT_F * IN_F) / 256, 256, 0, stream>>>(bw, sw, sc, Wc);
    kan_fused_kernel<<<(BATCH / BM) * (OUT_F / BN), 256, 0, stream>>>(x, Wc, (float*)d_out);
}